// Round 3
// baseline (128.022 us; speedup 1.0000x reference)
//
#include <hip/hip_runtime.h>
#include <math.h>

#define Bq 512
#define Nq 128
#define Mq 256
#define Eq 64
#define SM1 1023           // S-1 distance rows (s = 0..1022)
#define LOG2E 1.4426950408889634f

// Workspace layout (float offsets). Harness ws >= 1 GB; we use ~2.4 MB.
#define WS_ZC 0            // [512][128]  z_current per column
#define WS_A0 65536        // [4][512][128] partial A0
#define WS_A1 327680       // [4][512][128] partial A1
#define WS_MZ 589824       // [4][512][2]  partial {m, Z}

// Sum-reduce to all lanes WITHIN each 32-lane half of the wave.
// 4 DPP steps (quad xor1, quad xor2, row_half_mirror, row_mirror) + ds_swizzle xor16.
__device__ __forceinline__ float halfReduce32(float x) {
    x += __int_as_float(__builtin_amdgcn_update_dpp(0, __float_as_int(x), 0x0B1, 0xf, 0xf, true)); // quad_perm xor1
    x += __int_as_float(__builtin_amdgcn_update_dpp(0, __float_as_int(x), 0x04E, 0xf, 0xf, true)); // quad_perm xor2
    x += __int_as_float(__builtin_amdgcn_update_dpp(0, __float_as_int(x), 0x141, 0xf, 0xf, true)); // row_half_mirror (xor4)
    x += __int_as_float(__builtin_amdgcn_update_dpp(0, __float_as_int(x), 0x140, 0xf, 0xf, true)); // row_mirror (xor8)
    x += __int_as_float(__builtin_amdgcn_ds_swizzle(__float_as_int(x), 0x401F));                   // xor16 within 32
    return x;
}

// ---- kernel0: zc[col][o] = D[o,:]·z[:,col] + sigma[o]*noise[o,col] ----
extern "C" __global__ void __launch_bounds__(512)
zc_kernel(const float* __restrict__ z, const float* __restrict__ noise,
          const float* __restrict__ D, const float* __restrict__ sigma,
          float* __restrict__ ws)
{
    const int b4 = blockIdx.x * 4;
    const int t  = threadIdx.x;
    __shared__ float zs[4][256];
    for (int i = t; i < 1024; i += 512)
        zs[i >> 8][i & 255] = z[(i & 255) * Bq + b4 + (i >> 8)];
    __syncthreads();
    const int c = t >> 7, o = t & 127;
    const float4* Dr = (const float4*)(D + o * Mq);
    const float* zc = zs[c];
    float a0 = 0.f, a1 = 0.f, a2 = 0.f, a3 = 0.f;
    #pragma unroll 8
    for (int i = 0; i < 64; ++i) {
        float4 dv = Dr[i];
        a0 = fmaf(dv.x, zc[4 * i + 0], a0);
        a1 = fmaf(dv.y, zc[4 * i + 1], a1);
        a2 = fmaf(dv.z, zc[4 * i + 2], a2);
        a3 = fmaf(dv.w, zc[4 * i + 3], a3);
    }
    ws[WS_ZC + (b4 + c) * Nq + o] =
        (a0 + a1) + (a2 + a3) + sigma[o] * noise[o * Bq + b4 + c];
}

// One distance row. c = ring slot K (row RK), cn = row RK+1. Branchless online softmax.
#define ROW_BODY(K, RK, DOREFILL, CN)                                    \
    {                                                                    \
        float4 c  = buf[(K)];                                            \
        float4 cn = (CN);                                                \
        if (DOREFILL) buf[(K)] = p4[(size_t)((RK) + 16) * 16384];        \
        float d = (fabsf(c.x - zcv.x) + fabsf(c.y - zcv.y)) +            \
                  (fabsf(c.z - zcv.z) + fabsf(c.w - zcv.w));             \
        d = halfReduce32(d);                                             \
        float v = d * negt;                                              \
        float mnew = fmaxf(mrun, v);                                     \
        float sc = exp2f(mrun - mnew);                                   \
        float w  = exp2f(v - mnew);                                      \
        mrun = mnew;                                                     \
        Zrun = fmaf(Zrun, sc, w);                                        \
        a0.x = fmaf(a0.x, sc, w * c.x);                                  \
        a0.y = fmaf(a0.y, sc, w * c.y);                                  \
        a0.z = fmaf(a0.z, sc, w * c.z);                                  \
        a0.w = fmaf(a0.w, sc, w * c.w);                                  \
        a1.x = fmaf(a1.x, sc, w * cn.x);                                 \
        a1.y = fmaf(a1.y, sc, w * cn.y);                                 \
        a1.z = fmaf(a1.z, sc, w * cn.z);                                 \
        a1.w = fmaf(a1.w, sc, w * cn.w);                                 \
    }

// ---- kernel1: streaming pass. 1024 blocks = 256 column-pairs x 4 row-quarters.
// Each wave: 2 columns (one per 32-lane half), 32 rows, 1KB dwordx4 row loads.
extern "C" __global__ void __launch_bounds__(512, 8)
stream_kernel(const float* __restrict__ context,
              const float* __restrict__ temp1,
              float* __restrict__ ws)
{
    const int tid  = threadIdx.x;
    const int wave = tid >> 6;
    const int lane = tid & 63;
    const int half = lane >> 5;
    const int l5   = lane & 31;
    const int q    = blockIdx.x & 3;
    const int b0   = (blockIdx.x >> 2) * 2;

    __shared__ __align__(16) float sA0[8][2][128];
    __shared__ __align__(16) float sA1[8][2][128];
    __shared__ float sM[8][2];
    __shared__ float sZw[8][2];

    const int lo = q * 256 + wave * 32;
    const int hi = min(SM1, lo + 32);           // 32 rows (31 for the single last wave)

    // float4 view: row stride 16384 float4; this lane's 16B of the 1KB pair-chunk.
    const float4* p4 = (const float4*)context + (size_t)b0 * 32 + lane;

    float4 buf[16];
    #pragma unroll
    for (int j = 0; j < 16; ++j)
        buf[j] = p4[(size_t)(lo + j) * 16384];
    float4 cextra = p4[(size_t)hi * 16384];

    const float4 zcv = *(const float4*)(ws + WS_ZC + (size_t)(b0 + half) * Nq + l5 * 4);
    const float negt = -LOG2E / fabsf(temp1[0]);

    float mrun = -INFINITY, Zrun = 0.f;
    float4 a0 = make_float4(0.f, 0.f, 0.f, 0.f);
    float4 a1 = make_float4(0.f, 0.f, 0.f, 0.f);

    // main: rows lo..lo+15, refilling slot k with row lo+k+16 (always valid, never clamped)
    #pragma unroll
    for (int k = 0; k < 16; ++k)
        ROW_BODY(k, lo + k, 1, buf[(k + 1) & 15])
    // tail: rows lo+16..hi-1, data resident; last row's neighbor is cextra (= row hi)
    #pragma unroll
    for (int j = 0; j < 15; ++j) {
        if (lo + 16 + j < hi)
            ROW_BODY(j, lo + 16 + j, 0, buf[j + 1])
    }
    if (lo + 31 < hi)
        ROW_BODY(15, lo + 31, 0, cextra)

    *(float4*)&sA0[wave][half][l5 * 4] = a0;
    *(float4*)&sA1[wave][half][l5 * 4] = a1;
    if (l5 == 0) { sM[wave][half] = mrun; sZw[wave][half] = Zrun; }
    __syncthreads();

    // block-level merge of 8 wave states per column -> workspace partial
    const int c = (tid >> 7) & 1;
    const int o = tid & 127;
    float gm = sM[0][c];
    #pragma unroll
    for (int w = 1; w < 8; ++w) gm = fmaxf(gm, sM[w][c]);
    float scl[8];
    float Gz = 0.f;
    #pragma unroll
    for (int w = 0; w < 8; ++w) { scl[w] = exp2f(sM[w][c] - gm); Gz = fmaf(scl[w], sZw[w][c], Gz); }

    const size_t pslot = (size_t)q * Bq + b0 + c;
    if (tid < 256) {
        float acc = 0.f;
        #pragma unroll
        for (int w = 0; w < 8; ++w) acc = fmaf(scl[w], sA0[w][c][o], acc);
        ws[WS_A0 + pslot * Nq + o] = acc;
        if (o == 0) {
            ws[WS_MZ + pslot * 2]     = gm;
            ws[WS_MZ + pslot * 2 + 1] = Gz;
        }
    } else {
        float acc = 0.f;
        #pragma unroll
        for (int w = 0; w < 8; ++w) acc = fmaf(scl[w], sA1[w][c][o], acc);
        ws[WS_A1 + pslot * Nq + o] = acc;
    }
}

// ---- kernel2: merge 4 partials per column + conv-weight contraction + MLP + softmax ----
extern "C" __global__ void __launch_bounds__(128)
merge_kernel(const float* __restrict__ ws,
             const float* __restrict__ z,
             const float* __restrict__ conv_w,
             const float* __restrict__ conv_b,
             const float* __restrict__ W1,
             const float* __restrict__ b1,
             const float* __restrict__ W2,
             const float* __restrict__ b2,
             const float* __restrict__ temp2,
             float* __restrict__ out)
{
    const int col = blockIdx.x;
    const int t   = threadIdx.x;
    __shared__ __align__(16) float gA0[128];
    __shared__ __align__(16) float gA1[128];
    __shared__ __align__(16) float semb[128];
    __shared__ __align__(16) float szcol[256];
    __shared__ __align__(16) float shb[64];

    szcol[t]       = z[t * Bq + col];
    szcol[t + 128] = z[(t + 128) * Bq + col];

    float m[4], Zp[4];
    #pragma unroll
    for (int p = 0; p < 4; ++p) {
        m[p]  = ws[WS_MZ + ((size_t)p * Bq + col) * 2];
        Zp[p] = ws[WS_MZ + ((size_t)p * Bq + col) * 2 + 1];
    }
    float gm = fmaxf(fmaxf(m[0], m[1]), fmaxf(m[2], m[3]));
    float Gz = 0.f;
    float scl[4];
    #pragma unroll
    for (int p = 0; p < 4; ++p) { scl[p] = exp2f(m[p] - gm); Gz = fmaf(scl[p], Zp[p], Gz); }

    float acc0 = 0.f, acc1 = 0.f;
    #pragma unroll
    for (int p = 0; p < 4; ++p) {
        acc0 = fmaf(scl[p], ws[WS_A0 + ((size_t)p * Bq + col) * Nq + t], acc0);
        acc1 = fmaf(scl[p], ws[WS_A1 + ((size_t)p * Bq + col) * Nq + t], acc1);
    }
    gA0[t] = acc0;
    gA1[t] = acc1;
    __syncthreads();

    // embedding[o] = (w0[o,:]·A0 + w1[o,:]·A1)/Z + conv_b[o]
    {
        const float4* wr = (const float4*)(conv_w + t * 256);
        float acc = 0.f;
        #pragma unroll 8
        for (int i = 0; i < 64; ++i) {
            float4 w4 = wr[i];   // w0[o,2i], w1[o,2i], w0[o,2i+1], w1[o,2i+1]
            acc = fmaf(w4.x, gA0[2 * i], acc);
            acc = fmaf(w4.y, gA1[2 * i], acc);
            acc = fmaf(w4.z, gA0[2 * i + 1], acc);
            acc = fmaf(w4.w, gA1[2 * i + 1], acc);
        }
        semb[t] = acc / Gz + conv_b[t];
    }
    __syncthreads();

    if (t < 64) {
        const float4* w1r = (const float4*)(W1 + t * (Nq + Mq));
        float acc = b1[t];
        #pragma unroll 8
        for (int i = 0; i < 32; ++i) {
            float4 wv = w1r[i];
            acc = fmaf(wv.x, semb[4 * i + 0], acc);
            acc = fmaf(wv.y, semb[4 * i + 1], acc);
            acc = fmaf(wv.z, semb[4 * i + 2], acc);
            acc = fmaf(wv.w, semb[4 * i + 3], acc);
        }
        #pragma unroll 8
        for (int i = 0; i < 64; ++i) {
            float4 wv = w1r[32 + i];
            acc = fmaf(wv.x, szcol[4 * i + 0], acc);
            acc = fmaf(wv.y, szcol[4 * i + 1], acc);
            acc = fmaf(wv.z, szcol[4 * i + 2], acc);
            acc = fmaf(wv.w, szcol[4 * i + 3], acc);
        }
        shb[t] = fmaxf(acc, 0.f);
    }
    __syncthreads();

    if (t < 64) {
        const float* w2r = W2 + t * Eq;
        float acc = b2[t];
        #pragma unroll 8
        for (int j = 0; j < 64; ++j) acc = fmaf(w2r[j], shb[j], acc);
        float v = -acc * (LOG2E / fabsf(temp2[0]));
        float mx = v;
        #pragma unroll
        for (int off = 32; off > 0; off >>= 1) mx = fmaxf(mx, __shfl_xor(mx, off, 64));
        float w = exp2f(v - mx);
        float s = w;
        #pragma unroll
        for (int off = 32; off > 0; off >>= 1) s += __shfl_xor(s, off, 64);
        out[t * Bq + col] = w / s;
    }
}

extern "C" void kernel_launch(void* const* d_in, const int* in_sizes, int n_in,
                              void* d_out, int out_size, void* d_ws, size_t ws_size,
                              hipStream_t stream) {
    const float* context = (const float*)d_in[0];
    const float* z       = (const float*)d_in[1];
    const float* noise   = (const float*)d_in[2];
    const float* conv_w  = (const float*)d_in[3];
    const float* conv_b  = (const float*)d_in[4];
    const float* D       = (const float*)d_in[5];
    const float* sigma   = (const float*)d_in[6];
    const float* temp1   = (const float*)d_in[7];
    const float* W1      = (const float*)d_in[8];
    const float* b1      = (const float*)d_in[9];
    const float* W2      = (const float*)d_in[10];
    const float* b2      = (const float*)d_in[11];
    const float* temp2   = (const float*)d_in[12];
    float* out = (float*)d_out;
    float* ws  = (float*)d_ws;

    zc_kernel<<<dim3(128), dim3(512), 0, stream>>>(z, noise, D, sigma, ws);
    stream_kernel<<<dim3(1024), dim3(512), 0, stream>>>(context, temp1, ws);
    merge_kernel<<<dim3(512), dim3(128), 0, stream>>>(ws, z, conv_w, conv_b,
                                                      W1, b1, W2, b2, temp2, out);
}

// Round 4
// 81.779 us; speedup vs baseline: 1.5655x; 1.5655x over previous
//
#include <hip/hip_runtime.h>
#include <math.h>

#define Bq 512
#define Nq 128
#define Mq 256
#define Eq 64
#define SM1 1023           // S-1 distance rows (s = 0..1022)
#define LOG2E 1.4426950408889634f

// Workspace layout (float offsets). Harness ws >= 1 GB; we use ~2.4 MB.
#define WS_ZC 0            // [512][128]  z_current per column
#define WS_A0 65536        // [4][512][128] partial A0
#define WS_A1 327680       // [4][512][128] partial A1
#define WS_MZ 589824       // [4][512][2]  partial {m, Z}

// Sum-reduce to all lanes WITHIN each 32-lane half of the wave.
// 4 DPP steps (quad xor1, quad xor2, row_half_mirror, row_mirror) + ds_swizzle xor16.
__device__ __forceinline__ float halfReduce32(float x) {
    x += __int_as_float(__builtin_amdgcn_update_dpp(0, __float_as_int(x), 0x0B1, 0xf, 0xf, true)); // quad_perm xor1
    x += __int_as_float(__builtin_amdgcn_update_dpp(0, __float_as_int(x), 0x04E, 0xf, 0xf, true)); // quad_perm xor2
    x += __int_as_float(__builtin_amdgcn_update_dpp(0, __float_as_int(x), 0x141, 0xf, 0xf, true)); // row_half_mirror (xor4)
    x += __int_as_float(__builtin_amdgcn_update_dpp(0, __float_as_int(x), 0x140, 0xf, 0xf, true)); // row_mirror (xor8)
    x += __int_as_float(__builtin_amdgcn_ds_swizzle(__float_as_int(x), 0x401F));                   // xor16 within 32
    return x;
}

// ---- kernel0: zc[col][o] = D[o,:]·z[:,col] + sigma[o]*noise[o,col] ----
extern "C" __global__ void __launch_bounds__(512)
zc_kernel(const float* __restrict__ z, const float* __restrict__ noise,
          const float* __restrict__ D, const float* __restrict__ sigma,
          float* __restrict__ ws)
{
    const int b4 = blockIdx.x * 4;
    const int t  = threadIdx.x;
    __shared__ float zs[4][256];
    for (int i = t; i < 1024; i += 512)
        zs[i >> 8][i & 255] = z[(i & 255) * Bq + b4 + (i >> 8)];
    __syncthreads();
    const int c = t >> 7, o = t & 127;
    const float4* Dr = (const float4*)(D + o * Mq);
    const float* zc = zs[c];
    float a0 = 0.f, a1 = 0.f, a2 = 0.f, a3 = 0.f;
    #pragma unroll 8
    for (int i = 0; i < 64; ++i) {
        float4 dv = Dr[i];
        a0 = fmaf(dv.x, zc[4 * i + 0], a0);
        a1 = fmaf(dv.y, zc[4 * i + 1], a1);
        a2 = fmaf(dv.z, zc[4 * i + 2], a2);
        a3 = fmaf(dv.w, zc[4 * i + 3], a3);
    }
    ws[WS_ZC + (b4 + c) * Nq + o] =
        (a0 + a1) + (a2 + a3) + sigma[o] * noise[o * Bq + b4 + c];
}

// One distance row. c = ring slot K (row RK), cn = row RK+1. Branchless online softmax.
#define ROW_BODY(K, RK, DOREFILL, CN)                                    \
    {                                                                    \
        float4 c  = buf[(K)];                                            \
        float4 cn = (CN);                                                \
        if (DOREFILL) buf[(K)] = p4[(size_t)((RK) + 16) * 16384];        \
        float d = (fabsf(c.x - zcv.x) + fabsf(c.y - zcv.y)) +            \
                  (fabsf(c.z - zcv.z) + fabsf(c.w - zcv.w));             \
        d = halfReduce32(d);                                             \
        float v = d * negt;                                              \
        float mnew = fmaxf(mrun, v);                                     \
        float sc = exp2f(mrun - mnew);                                   \
        float w  = exp2f(v - mnew);                                      \
        mrun = mnew;                                                     \
        Zrun = fmaf(Zrun, sc, w);                                        \
        a0.x = fmaf(a0.x, sc, w * c.x);                                  \
        a0.y = fmaf(a0.y, sc, w * c.y);                                  \
        a0.z = fmaf(a0.z, sc, w * c.z);                                  \
        a0.w = fmaf(a0.w, sc, w * c.w);                                  \
        a1.x = fmaf(a1.x, sc, w * cn.x);                                 \
        a1.y = fmaf(a1.y, sc, w * cn.y);                                 \
        a1.z = fmaf(a1.z, sc, w * cn.z);                                 \
        a1.w = fmaf(a1.w, sc, w * cn.w);                                 \
    }

// ---- kernel1: streaming pass. 1024 blocks = 256 column-pairs x 4 row-quarters.
// Each wave: 2 columns (one per 32-lane half), 32 rows, 1KB dwordx4 row loads.
// launch_bounds(512, 4): 128-VGPR cap -- ring(64)+state(~35) fits, NO spill.
// (R3's (512,8) capped at 64 VGPRs -> full ring spilled to scratch -> 128us.)
extern "C" __global__ void __launch_bounds__(512, 4)
stream_kernel(const float* __restrict__ context,
              const float* __restrict__ temp1,
              float* __restrict__ ws)
{
    const int tid  = threadIdx.x;
    const int wave = tid >> 6;
    const int lane = tid & 63;
    const int half = lane >> 5;
    const int l5   = lane & 31;
    const int q    = blockIdx.x & 3;
    const int b0   = (blockIdx.x >> 2) * 2;

    __shared__ __align__(16) float sA0[8][2][128];
    __shared__ __align__(16) float sA1[8][2][128];
    __shared__ float sM[8][2];
    __shared__ float sZw[8][2];

    const int lo = q * 256 + wave * 32;
    const int hi = min(SM1, lo + 32);           // 32 rows (31 for the single last wave)

    // float4 view: row stride 16384 float4; this lane's 16B of the 1KB pair-chunk.
    const float4* p4 = (const float4*)context + (size_t)b0 * 32 + lane;

    float4 buf[16];
    #pragma unroll
    for (int j = 0; j < 16; ++j)
        buf[j] = p4[(size_t)(lo + j) * 16384];
    float4 cextra = p4[(size_t)hi * 16384];

    const float4 zcv = *(const float4*)(ws + WS_ZC + (size_t)(b0 + half) * Nq + l5 * 4);
    const float negt = -LOG2E / fabsf(temp1[0]);

    float mrun = -INFINITY, Zrun = 0.f;
    float4 a0 = make_float4(0.f, 0.f, 0.f, 0.f);
    float4 a1 = make_float4(0.f, 0.f, 0.f, 0.f);

    // main: rows lo..lo+15, refilling slot k with row lo+k+16 (always valid, never clamped)
    #pragma unroll
    for (int k = 0; k < 16; ++k)
        ROW_BODY(k, lo + k, 1, buf[(k + 1) & 15])
    // tail: rows lo+16..hi-1, data resident; last row's neighbor is cextra (= row hi)
    #pragma unroll
    for (int j = 0; j < 15; ++j) {
        if (lo + 16 + j < hi)
            ROW_BODY(j, lo + 16 + j, 0, buf[j + 1])
    }
    if (lo + 31 < hi)
        ROW_BODY(15, lo + 31, 0, cextra)

    *(float4*)&sA0[wave][half][l5 * 4] = a0;
    *(float4*)&sA1[wave][half][l5 * 4] = a1;
    if (l5 == 0) { sM[wave][half] = mrun; sZw[wave][half] = Zrun; }
    __syncthreads();

    // block-level merge of 8 wave states per column -> workspace partial
    const int c = (tid >> 7) & 1;
    const int o = tid & 127;
    float gm = sM[0][c];
    #pragma unroll
    for (int w = 1; w < 8; ++w) gm = fmaxf(gm, sM[w][c]);
    float scl[8];
    float Gz = 0.f;
    #pragma unroll
    for (int w = 0; w < 8; ++w) { scl[w] = exp2f(sM[w][c] - gm); Gz = fmaf(scl[w], sZw[w][c], Gz); }

    const size_t pslot = (size_t)q * Bq + b0 + c;
    if (tid < 256) {
        float acc = 0.f;
        #pragma unroll
        for (int w = 0; w < 8; ++w) acc = fmaf(scl[w], sA0[w][c][o], acc);
        ws[WS_A0 + pslot * Nq + o] = acc;
        if (o == 0) {
            ws[WS_MZ + pslot * 2]     = gm;
            ws[WS_MZ + pslot * 2 + 1] = Gz;
        }
    } else {
        float acc = 0.f;
        #pragma unroll
        for (int w = 0; w < 8; ++w) acc = fmaf(scl[w], sA1[w][c][o], acc);
        ws[WS_A1 + pslot * Nq + o] = acc;
    }
}

// ---- kernel2: merge 4 partials per column + conv-weight contraction + MLP + softmax ----
extern "C" __global__ void __launch_bounds__(128)
merge_kernel(const float* __restrict__ ws,
             const float* __restrict__ z,
             const float* __restrict__ conv_w,
             const float* __restrict__ conv_b,
             const float* __restrict__ W1,
             const float* __restrict__ b1,
             const float* __restrict__ W2,
             const float* __restrict__ b2,
             const float* __restrict__ temp2,
             float* __restrict__ out)
{
    const int col = blockIdx.x;
    const int t   = threadIdx.x;
    __shared__ __align__(16) float gA0[128];
    __shared__ __align__(16) float gA1[128];
    __shared__ __align__(16) float semb[128];
    __shared__ __align__(16) float szcol[256];
    __shared__ __align__(16) float shb[64];

    szcol[t]       = z[t * Bq + col];
    szcol[t + 128] = z[(t + 128) * Bq + col];

    float m[4], Zp[4];
    #pragma unroll
    for (int p = 0; p < 4; ++p) {
        m[p]  = ws[WS_MZ + ((size_t)p * Bq + col) * 2];
        Zp[p] = ws[WS_MZ + ((size_t)p * Bq + col) * 2 + 1];
    }
    float gm = fmaxf(fmaxf(m[0], m[1]), fmaxf(m[2], m[3]));
    float Gz = 0.f;
    float scl[4];
    #pragma unroll
    for (int p = 0; p < 4; ++p) { scl[p] = exp2f(m[p] - gm); Gz = fmaf(scl[p], Zp[p], Gz); }

    float acc0 = 0.f, acc1 = 0.f;
    #pragma unroll
    for (int p = 0; p < 4; ++p) {
        acc0 = fmaf(scl[p], ws[WS_A0 + ((size_t)p * Bq + col) * Nq + t], acc0);
        acc1 = fmaf(scl[p], ws[WS_A1 + ((size_t)p * Bq + col) * Nq + t], acc1);
    }
    gA0[t] = acc0;
    gA1[t] = acc1;
    __syncthreads();

    // embedding[o] = (w0[o,:]·A0 + w1[o,:]·A1)/Z + conv_b[o]
    {
        const float4* wr = (const float4*)(conv_w + t * 256);
        float acc = 0.f;
        #pragma unroll 8
        for (int i = 0; i < 64; ++i) {
            float4 w4 = wr[i];   // w0[o,2i], w1[o,2i], w0[o,2i+1], w1[o,2i+1]
            acc = fmaf(w4.x, gA0[2 * i], acc);
            acc = fmaf(w4.y, gA1[2 * i], acc);
            acc = fmaf(w4.z, gA0[2 * i + 1], acc);
            acc = fmaf(w4.w, gA1[2 * i + 1], acc);
        }
        semb[t] = acc / Gz + conv_b[t];
    }
    __syncthreads();

    if (t < 64) {
        const float4* w1r = (const float4*)(W1 + t * (Nq + Mq));
        float acc = b1[t];
        #pragma unroll 8
        for (int i = 0; i < 32; ++i) {
            float4 wv = w1r[i];
            acc = fmaf(wv.x, semb[4 * i + 0], acc);
            acc = fmaf(wv.y, semb[4 * i + 1], acc);
            acc = fmaf(wv.z, semb[4 * i + 2], acc);
            acc = fmaf(wv.w, semb[4 * i + 3], acc);
        }
        #pragma unroll 8
        for (int i = 0; i < 64; ++i) {
            float4 wv = w1r[32 + i];
            acc = fmaf(wv.x, szcol[4 * i + 0], acc);
            acc = fmaf(wv.y, szcol[4 * i + 1], acc);
            acc = fmaf(wv.z, szcol[4 * i + 2], acc);
            acc = fmaf(wv.w, szcol[4 * i + 3], acc);
        }
        shb[t] = fmaxf(acc, 0.f);
    }
    __syncthreads();

    if (t < 64) {
        const float* w2r = W2 + t * Eq;
        float acc = b2[t];
        #pragma unroll 8
        for (int j = 0; j < 64; ++j) acc = fmaf(w2r[j], shb[j], acc);
        float v = -acc * (LOG2E / fabsf(temp2[0]));
        float mx = v;
        #pragma unroll
        for (int off = 32; off > 0; off >>= 1) mx = fmaxf(mx, __shfl_xor(mx, off, 64));
        float w = exp2f(v - mx);
        float s = w;
        #pragma unroll
        for (int off = 32; off > 0; off >>= 1) s += __shfl_xor(s, off, 64);
        out[t * Bq + col] = w / s;
    }
}

extern "C" void kernel_launch(void* const* d_in, const int* in_sizes, int n_in,
                              void* d_out, int out_size, void* d_ws, size_t ws_size,
                              hipStream_t stream) {
    const float* context = (const float*)d_in[0];
    const float* z       = (const float*)d_in[1];
    const float* noise   = (const float*)d_in[2];
    const float* conv_w  = (const float*)d_in[3];
    const float* conv_b  = (const float*)d_in[4];
    const float* D       = (const float*)d_in[5];
    const float* sigma   = (const float*)d_in[6];
    const float* temp1   = (const float*)d_in[7];
    const float* W1      = (const float*)d_in[8];
    const float* b1      = (const float*)d_in[9];
    const float* W2      = (const float*)d_in[10];
    const float* b2      = (const float*)d_in[11];
    const float* temp2   = (const float*)d_in[12];
    float* out = (float*)d_out;
    float* ws  = (float*)d_ws;

    zc_kernel<<<dim3(128), dim3(512), 0, stream>>>(z, noise, D, sigma, ws);
    stream_kernel<<<dim3(1024), dim3(512), 0, stream>>>(context, temp1, ws);
    merge_kernel<<<dim3(512), dim3(128), 0, stream>>>(ws, z, conv_w, conv_b,
                                                      W1, b1, W2, b2, temp2, out);
}